// Round 6
// baseline (48.037 us; speedup 1.0000x reference)
//
#include <hip/hip_runtime.h>

// WHXE loss, round 6: single fused kernel (memset + fused pass1/epilogue).
//   colS[n] = sum_b lam[n] * logp[b,n] * true[b,n]
//   cnt[n]  = sum_b true[b,n]
//   loss    = -(1/B) * sum_n (B / (N*(cnt[n]+eps))) * colS[n]
// Sibling groups are 4 consecutive columns -> one float4 = one softmax group.
//
// LESSONS: (R3) NO per-block device-scope __threadfence on gfx950 — it emits
// an L2 writeback/invalidate per block and serialized the chip (370 µs).
// Ordering here uses only: per-wave s_waitcnt vmcnt(0) (atomics are
// vmcnt-tracked) + relaxed agent-scope atomics at the coherence point.
// (R2-R5) pass1 is at a ~5.2 TB/s fabric ceiling: 2-deep VGPR pipeline,
// batched loads, and LDS-DMA prefetch all tie -> keep the simplest body.

#define B_TOTAL 131072
#define N_NODES 128
#define ALPHA   0.5f
#define EPS     1e-10f

constexpr int BLOCKS         = 2048;
constexpr int THREADS        = 256;
constexpr int ROWS_PER_ITER  = THREADS / 32;                    // 8
constexpr int ROWS_PER_BLOCK = B_TOTAL / BLOCKS;                // 64
constexpr int ITERS          = ROWS_PER_BLOCK / ROWS_PER_ITER;  // 8 (compile-time)
constexpr int REPLICAS       = 32;

__global__ __launch_bounds__(THREADS, 8) void whxe_fused(
    const float* __restrict__ logits,
    const float* __restrict__ truev,
    const float* __restrict__ depths,
    float* __restrict__ ws,          // [REPLICAS*256] accum + 1 uint done-ctr
    float* __restrict__ out)
{
    const int t    = threadIdx.x;
    const int cg   = t & 31;          // column group 0..31 (4 cols each)
    const int rsub = t >> 5;          // row-within-iteration 0..7
    const int c0   = cg << 2;

    float lam[4];
#pragma unroll
    for (int i = 0; i < 4; ++i) lam[i] = __expf(-ALPHA * depths[c0 + i]);

    const size_t base0 = (size_t)(blockIdx.x * ROWS_PER_BLOCK + rsub) * N_NODES + c0;
    const float* lp = logits + base0;
    const float* tp = truev  + base0;
    constexpr size_t STRIDE = (size_t)ROWS_PER_ITER * N_NODES;  // 1024 elems

    float colS[4] = {0.f, 0.f, 0.f, 0.f};
    float cnt [4] = {0.f, 0.f, 0.f, 0.f};

#pragma unroll
    for (int it = 0; it < ITERS; ++it) {
        const float4 x  = *reinterpret_cast<const float4*>(lp + (size_t)it * STRIDE);
        const float4 tv = *reinterpret_cast<const float4*>(tp + (size_t)it * STRIDE);
        const float e0 = __expf(x.x), e1 = __expf(x.y),
                    e2 = __expf(x.z), e3 = __expf(x.w);
        const float ld = __logf(e0 + e1 + e2 + e3 + EPS);
        colS[0] += lam[0] * (x.x - ld) * tv.x;  cnt[0] += tv.x;
        colS[1] += lam[1] * (x.y - ld) * tv.y;  cnt[1] += tv.y;
        colS[2] += lam[2] * (x.z - ld) * tv.z;  cnt[2] += tv.z;
        colS[3] += lam[3] * (x.w - ld) * tv.w;  cnt[3] += tv.w;
    }

    // block reduction: 8 accumulators/thread -> 256 partials
    __shared__ float lds[8][THREADS];
#pragma unroll
    for (int i = 0; i < 4; ++i) {
        lds[i][t]     = colS[i];
        lds[4 + i][t] = cnt[i];
    }
    __syncthreads();

    const int q   = t >> 7;           // 0 = colS, 1 = cnt
    const int c   = t & 127;          // column
    const int acc = q * 4 + (c & 3);
    const int cgr = c >> 2;
    float s = 0.f;
#pragma unroll
    for (int r = 0; r < 8; ++r) s += lds[acc][r * 32 + cgr];

    // replica-spread device-scope atomics (64 adds/address, proven R2)
    const int rep = blockIdx.x & (REPLICAS - 1);
    atomicAdd(&ws[rep * 256 + q * 128 + c], s);

    // ---- completion signal: NO threadfence. vmcnt tracks the atomic; once
    // it is acked at the coherence point, this block's contribution is
    // globally visible to agent-scope readers. ----
    asm volatile("s_waitcnt vmcnt(0)" ::: "memory");
    __syncthreads();                 // all 4 waves' atomics acked

    __shared__ int lastFlag;
    if (t == 0) {
        unsigned* ctr = (unsigned*)(ws + REPLICAS * 256);
        unsigned old = __hip_atomic_fetch_add(ctr, 1u, __ATOMIC_RELAXED,
                                              __HIP_MEMORY_SCOPE_AGENT);
        lastFlag = (old == (unsigned)(BLOCKS - 1));
    }
    __syncthreads();
    if (!lastFlag) return;

    // ---- last block: fold replicas via coherence-point loads ----
    float fs = 0.f;
#pragma unroll
    for (int r = 0; r < REPLICAS; ++r)
        fs += __hip_atomic_load(&ws[r * 256 + t], __ATOMIC_RELAXED,
                                __HIP_MEMORY_SCOPE_AGENT);
    __shared__ float red[256];
    red[t] = fs;
    __syncthreads();

    if (t < 64) {
        float v = 0.f;
#pragma unroll
        for (int cc = t; cc < 128; cc += 64) {
            const float w = (float)B_TOTAL / ((float)N_NODES * (red[128 + cc] + EPS));
            v += w * red[cc];
        }
#pragma unroll
        for (int off = 32; off; off >>= 1) v += __shfl_xor(v, off);
        if (t == 0) out[0] = -v / (float)B_TOTAL;
    }
}

extern "C" void kernel_launch(void* const* d_in, const int* in_sizes, int n_in,
                              void* d_out, int out_size, void* d_ws, size_t ws_size,
                              hipStream_t stream) {
    const float* logits = (const float*)d_in[0];
    const float* truev  = (const float*)d_in[1];
    const float* depths = (const float*)d_in[2];
    float* ws = (float*)d_ws;

    // zero accumulators + done-counter (needed every call; graph-legal)
    hipMemsetAsync(ws, 0, REPLICAS * 256 * sizeof(float) + sizeof(unsigned),
                   stream);
    whxe_fused<<<BLOCKS, THREADS, 0, stream>>>(logits, truev, depths, ws,
                                               (float*)d_out);
}

// Round 8
// 31.595 us; speedup vs baseline: 1.5204x; 1.5204x over previous
//
#include <hip/hip_runtime.h>

// WHXE loss, round 8: R2 structure + nontemporal input loads (compile-fixed:
// __builtin_nontemporal_load needs a native vector type, not HIP_vector_type).
//   colS[n] = sum_b lam[n] * logp[b,n] * true[b,n]
//   cnt[n]  = sum_b true[b,n]
//   loss    = -(1/B) * sum_n (B / (N*(cnt[n]+eps))) * colS[n]
// Sibling groups are 4 consecutive columns -> one native-float4 = one group.
// LESSONS: (R3) no per-block device-scope fences (L2 WB/INV storm, 370 µs);
// (R4) compiler won't keep VGPR load batches in flight; (R5) LDS-DMA ties;
// (R6) last-block fusion costs more than the dispatch it saves (48 µs).

#define B_TOTAL 131072
#define N_NODES 128
#define ALPHA   0.5f
#define EPS     1e-10f

typedef float vfloat4 __attribute__((ext_vector_type(4)));

constexpr int BLOCKS         = 2048;
constexpr int THREADS        = 256;
constexpr int ROWS_PER_ITER  = THREADS / 32;                    // 8
constexpr int ROWS_PER_BLOCK = B_TOTAL / BLOCKS;                // 64
constexpr int ITERS          = ROWS_PER_BLOCK / ROWS_PER_ITER;  // 8 (compile-time)
constexpr int REPLICAS       = 32;

__global__ __launch_bounds__(THREADS, 8) void whxe_pass1(
    const float* __restrict__ logits,
    const float* __restrict__ truev,
    const float* __restrict__ depths,
    float* __restrict__ ws)   // ws[rep][256]: [0..127]=colS, [128..255]=cnt
{
    const int t    = threadIdx.x;
    const int cg   = t & 31;          // column group 0..31 (4 cols each)
    const int rsub = t >> 5;          // row-within-iteration 0..7
    const int c0   = cg << 2;

    float lam[4];
#pragma unroll
    for (int i = 0; i < 4; ++i) lam[i] = __expf(-ALPHA * depths[c0 + i]);

    const size_t base0 = (size_t)(blockIdx.x * ROWS_PER_BLOCK + rsub) * N_NODES + c0;
    const float* lp = logits + base0;
    const float* tp = truev  + base0;
    constexpr size_t STRIDE = (size_t)ROWS_PER_ITER * N_NODES;  // 1024 elems

    float colS[4] = {0.f, 0.f, 0.f, 0.f};
    float cnt [4] = {0.f, 0.f, 0.f, 0.f};

    // 2-deep pipeline, nt loads (streaming: no L2 allocate)
    vfloat4 x  = __builtin_nontemporal_load(reinterpret_cast<const vfloat4*>(lp));
    vfloat4 tv = __builtin_nontemporal_load(reinterpret_cast<const vfloat4*>(tp));
#pragma unroll
    for (int it = 0; it < ITERS; ++it) {
        vfloat4 xn = {0.f, 0.f, 0.f, 0.f}, tvn = {0.f, 0.f, 0.f, 0.f};
        if (it + 1 < ITERS) {
            xn  = __builtin_nontemporal_load(
                      reinterpret_cast<const vfloat4*>(lp + (size_t)(it + 1) * STRIDE));
            tvn = __builtin_nontemporal_load(
                      reinterpret_cast<const vfloat4*>(tp + (size_t)(it + 1) * STRIDE));
        }
        const float e0 = __expf(x.x), e1 = __expf(x.y),
                    e2 = __expf(x.z), e3 = __expf(x.w);
        const float ld = __logf(e0 + e1 + e2 + e3 + EPS);
        colS[0] += lam[0] * (x.x - ld) * tv.x;  cnt[0] += tv.x;
        colS[1] += lam[1] * (x.y - ld) * tv.y;  cnt[1] += tv.y;
        colS[2] += lam[2] * (x.z - ld) * tv.z;  cnt[2] += tv.z;
        colS[3] += lam[3] * (x.w - ld) * tv.w;  cnt[3] += tv.w;
        x = xn; tv = tvn;
    }

    // block reduction: 8 accumulators/thread -> 256 partials
    __shared__ float lds[8][THREADS];
#pragma unroll
    for (int i = 0; i < 4; ++i) {
        lds[i][t]     = colS[i];
        lds[4 + i][t] = cnt[i];
    }
    __syncthreads();

    const int q   = t >> 7;           // 0 = colS, 1 = cnt
    const int c   = t & 127;          // column
    const int acc = q * 4 + (c & 3);
    const int cgr = c >> 2;
    float s = 0.f;
#pragma unroll
    for (int r = 0; r < 8; ++r) s += lds[acc][r * 32 + cgr];

    // replica-spread atomics: 64 adds per address (proven R2)
    const int rep = blockIdx.x & (REPLICAS - 1);
    atomicAdd(&ws[rep * 256 + q * 128 + c], s);
}

__global__ __launch_bounds__(256) void whxe_pass2(
    const float* __restrict__ ws, float* __restrict__ out)
{
    const int t = threadIdx.x;        // 256
    float s = 0.f;
#pragma unroll
    for (int r = 0; r < REPLICAS; ++r) s += ws[r * 256 + t];

    __shared__ float red[256];
    red[t] = s;
    __syncthreads();

    if (t < 64) {
        float v = 0.f;
#pragma unroll
        for (int cc = t; cc < 128; cc += 64) {
            const float w = (float)B_TOTAL / ((float)N_NODES * (red[128 + cc] + EPS));
            v += w * red[cc];
        }
#pragma unroll
        for (int off = 32; off; off >>= 1) v += __shfl_xor(v, off);
        if (t == 0) out[0] = -v / (float)B_TOTAL;
    }
}

extern "C" void kernel_launch(void* const* d_in, const int* in_sizes, int n_in,
                              void* d_out, int out_size, void* d_ws, size_t ws_size,
                              hipStream_t stream) {
    const float* logits = (const float*)d_in[0];
    const float* truev  = (const float*)d_in[1];
    const float* depths = (const float*)d_in[2];
    float* ws = (float*)d_ws;

    hipMemsetAsync(ws, 0, REPLICAS * 256 * sizeof(float), stream);
    whxe_pass1<<<BLOCKS, THREADS, 0, stream>>>(logits, truev, depths, ws);
    whxe_pass2<<<1, 256, 0, stream>>>(ws, (float*)d_out);
}